// Round 10
// baseline (205.176 us; speedup 1.0000x reference)
//
#include <hip/hip_runtime.h>

#define Dm 96
#define PL (Dm*Dm*Dm)               // 884736 elements per (b, ic) plane
#define ICn 16
#define OCn 16
#define HYPn 128
#define BSn 4
// K-packing: 15 groups of K=32. grp = ty*5 + g (ty = ky tap 0..2, g = 0..4).
// k_local = cl*16 + ic, cl in {0,1} -> (kz,kx) combo c = 2g+cl (c=9 is padding).
#define NG 15
#define FRAG_ELEMS (NG*64*8)        // 7680 bf16 per sample

// xT: bf16 [b][z:-1..96][y:-1..96][x:-1..96][16ic], 32B per point, zero halo.
#define XP 98
#define ROWB (XP*32)                // 3136
#define PLANEB (XP*ROWB)            // 307328
#define SAMPB ((size_t)XP*PLANEB)   // 30118144
#define XT_TOTAL ((size_t)4*SAMPB)  // 120472576

typedef float   f32x4  __attribute__((ext_vector_type(4)));
typedef __bf16  bf16x8 __attribute__((ext_vector_type(8)));

__device__ __forceinline__ unsigned short f2bf(float f) {
    unsigned u = __builtin_bit_cast(unsigned, f);
    u = (u + 0x7FFFu + ((u >> 16) & 1u)) >> 16;
    return (unsigned short)u;
}

// ---------------- transpose/convert pre-pass ----------------
// blocks 0..1535: (b, z, y-quarter) interior; blocks 1536..1543: z-border planes.
__global__ __launch_bounds__(256)
void transpose_kernel(const float* __restrict__ x, char* __restrict__ xT)
{
    int blk = blockIdx.x;
    if (blk >= 1536) {                      // zero z = -1 / 96 full planes
        int idx = blk - 1536;
        int b = idx >> 1, zb = idx & 1;
        char* p = xT + (size_t)b*SAMPB + (size_t)(zb ? 97 : 0)*PLANEB;
        f32x4 z4 = {0.f,0.f,0.f,0.f};
        for (int i = threadIdx.x; i < PLANEB/16; i += 256)
            *(f32x4*)(p + (size_t)i*16) = z4;
        return;
    }
    int yq = blk & 3;
    int z  = (blk >> 2) % Dm;
    int b  = (blk >> 2) / Dm;
    char* xTp = xT + (size_t)b*SAMPB + (size_t)(z+1)*PLANEB;
    const float* xb = x + (size_t)b*ICn*PL + (size_t)z*Dm*Dm;

    // interior: 576 tasks = 24 rows x 24 x-quads
    for (int t = threadIdx.x; t < 576; t += 256) {
        int q = t % 24, yy = t / 24;
        int y = yq*24 + yy;
        const float* g = xb + y*Dm + 4*q;
        f32x4 ld[16];
#pragma unroll
        for (int ic = 0; ic < 16; ++ic)
            ld[ic] = *(const f32x4*)(g + (size_t)ic*PL);
        char* w = xTp + (size_t)(y+1)*ROWB + (size_t)(1 + 4*q)*32;
#pragma unroll
        for (int xi = 0; xi < 4; ++xi) {
            bf16x8 lo, hi;
#pragma unroll
            for (int ic = 0; ic < 8; ++ic) { lo[ic] = (__bf16)ld[ic][xi]; hi[ic] = (__bf16)ld[8+ic][xi]; }
            *(bf16x8*)(w + xi*32)      = lo;
            *(bf16x8*)(w + xi*32 + 16) = hi;
        }
    }
    // x-halo zeros for this block's 24 rows
    bf16x8 z8;
#pragma unroll
    for (int i = 0; i < 8; ++i) z8[i] = (__bf16)0.f;
    for (int t = threadIdx.x; t < 96; t += 256) {
        int half = t & 1, side = (t >> 1) & 1, yy = t >> 2;
        int y = yq*24 + yy;
        *(bf16x8*)(xTp + (size_t)(y+1)*ROWB + (size_t)(side ? 97 : 0)*32 + half*16) = z8;
    }
    // y-halo rows
    if (yq == 0 || yq == 3) {
        char* w0 = xTp + (size_t)(yq == 0 ? 0 : 97)*ROWB;
        for (int t = threadIdx.x; t < XP*2; t += 256)
            *(bf16x8*)(w0 + (size_t)t*16) = z8;
    }
}

// ---------------- hypernetwork: A-fragments in MFMA lane order ----------------
__global__ __launch_bounds__(256)
void hyper_frag_kernel(const float* __restrict__ hyp, const float* __restrict__ Wk,
                       const float* __restrict__ bk, unsigned short* __restrict__ kwf)
{
    int t = blockIdx.x * 256 + threadIdx.x;
    if (t >= BSn * FRAG_ELEMS) return;
    int j    = t & 7;
    int lane = (t >> 3) & 63;
    int rest = t >> 9;
    int grp  = rest % NG;
    int b    = rest / NG;
    int oc = lane & 15, hi = lane >> 4;
    int ty = grp / 5, g = grp % 5;
    int cl = hi >> 1;
    int ic = (hi & 1) * 8 + j;
    int c  = 2 * g + cl;
    float acc = 0.f;
    if (c < 9) {
        int tz = c / 3, tx = c % 3;
        int r = (oc * ICn + ic) * 27 + (tz * 9 + ty * 3 + tx);
        const float4* w = (const float4*)(Wk + (long)r * HYPn);
        const float4* h = (const float4*)(hyp + (long)b * HYPn);
        acc = bk[r];
#pragma unroll
        for (int q = 0; q < HYPn / 4; ++q) {
            float4 a = h[q], cc = w[q];
            acc += a.x * cc.x + a.y * cc.y + a.z * cc.z + a.w * cc.w;
        }
    }
    kwf[t] = f2bf(acc);
}

__global__ __launch_bounds__(64)
void hyper_bias_kernel(const float* __restrict__ hyp, const float* __restrict__ Wb,
                       const float* __restrict__ bb, float* __restrict__ bias)
{
    int t = threadIdx.x;
    int b = t >> 4, oc = t & 15;
    const float4* w = (const float4*)(Wb + (long)oc * HYPn);
    const float4* h = (const float4*)(hyp + (long)b * HYPn);
    float acc = bb[oc];
#pragma unroll
    for (int q = 0; q < HYPn / 4; ++q) {
        float4 a = h[q], c = w[q];
        acc += a.x * c.x + a.y * c.y + a.z * c.z + a.w * c.w;
    }
    bias[t] = acc;
}

// ---------------- MFMA conv: DMA-staged, double-buffered z-tile pipeline -----
#define ZT 4
#define YT 8
#define XT 16
#define ZL 6
#define YL 10
#define XL 18
#define SSTR 32
#define SPN (ZL*YL*XL)              // 1080
#define LPTS 1088                   // padded to DMA granularity
#define LDSB (LPTS*SSTR)            // 34816 per buffer
#define NDMA 34
#define NT 4
#define ZCH (ZT*NT)                 // 16

__device__ constexpr int coff(int c) {
    return ((c / 3) * YL * XL + (c % 3)) * SSTR;
}

__device__ __forceinline__ void dma_tile(const char* org, char* buf,
                                         const unsigned* goff, int wz, int lane)
{
#pragma unroll
    for (int m = 0; m < 9; ++m) {
        if (wz + 4*m < NDMA) {
            int i = wz + 4*m;
            __builtin_amdgcn_global_load_lds(
                (const __attribute__((address_space(1))) unsigned int*)(org + goff[m]),
                (__attribute__((address_space(3))) unsigned int*)(buf + i*1024 + lane*16),
                16, 0, 0);
        }
    }
}

__global__ __launch_bounds__(256, 2)
void conv_dma_kernel(const char* __restrict__ xT, const unsigned short* __restrict__ kwf,
                     const float* __restrict__ bias, float* __restrict__ out)
{
    __shared__ __align__(16) char smem[2*LDSB];

    const int NB = BSn * 6 * 12 * 6;                 // 1728
    int raw = blockIdx.x;
    int u = (raw & 7) * (NB/8) + (raw >> 3);         // XCD-contiguous

    int tx = u % 6;  u /= 6;
    int ty = u % 12; u /= 12;
    int zc = u % 6;
    int b  = u / 6;
    int x0 = tx*XT, y0 = ty*YT, zbase = zc*ZCH;

    int tid  = threadIdx.x;
    int lane = tid & 63;
    int wz   = tid >> 6;

    const unsigned short* kwb = kwf + (long)b * FRAG_ELEMS;
    f32x4 afr[NG];
#pragma unroll
    for (int grp = 0; grp < NG; ++grp) {
        afr[grp] = *(const f32x4*)(kwb + (grp * 64 + lane) * 8);
        asm volatile("" : "+v"(afr[grp]));
    }

    unsigned goff[9];
#pragma unroll
    for (int m = 0; m < 9; ++m) {
        int i = wz + 4*m;
        if (i >= NDMA) i = NDMA - 1;
        int flat = i*64 + lane;
        int p = flat >> 1;  if (p > 1079) p = 1079;
        int half = flat & 1;
        int lz = p / (YL*XL), r = p % (YL*XL), ly = r / XL, lx = r % XL;
        goff[m] = (unsigned)(lz*PLANEB + ly*ROWB + lx*32 + half*16);
    }

    int n   = lane & 15;
    int hi  = lane >> 4;
    int cl  = hi >> 1;
    int ich = hi & 1;

    int addr_g[5];
#pragma unroll
    for (int g = 0; g < 5; ++g) {
        int c = 2 * g + cl;
        if (c > 8) c = 8;
        addr_g[g] = ((wz * YL) * XL + n) * SSTR + ich * 16 + coff(c);
    }

    float4 bv = *(const float4*)(bias + b * OCn + hi * 4);

    const char* xsamp = xT + (size_t)b*SAMPB + (size_t)y0*ROWB + (size_t)x0*32;

    char* buf0 = smem;
    char* buf1 = smem + LDSB;

    dma_tile(xsamp + (size_t)zbase*PLANEB, buf0, goff, wz, lane);
    __syncthreads();

#pragma unroll
    for (int t = 0; t < NT; ++t) {
        char* cur = (t & 1) ? buf1 : buf0;
        char* nxt = (t & 1) ? buf0 : buf1;
        int ztile = zbase + t*ZT;

        if (t + 1 < NT)
            dma_tile(xsamp + (size_t)(ztile + ZT)*PLANEB, nxt, goff, wz, lane);

        f32x4 acc[YT];
#pragma unroll
        for (int yy = 0; yy < YT; ++yy) acc[yy] = (f32x4){0.f,0.f,0.f,0.f};

#pragma unroll
        for (int p = 0; p < YL; ++p) {
            bf16x8 F[5];
#pragma unroll
            for (int g = 0; g < 5; ++g)
                F[g] = *(const bf16x8*)(cur + addr_g[g] + p * (XL * SSTR));
#pragma unroll
            for (int tyk = 0; tyk < 3; ++tyk) {
                int yy = p - tyk;
                if (yy >= 0 && yy < YT) {
#pragma unroll
                    for (int g = 0; g < 5; ++g)
                        acc[yy] = __builtin_amdgcn_mfma_f32_16x16x32_bf16(
                            __builtin_bit_cast(bf16x8, afr[tyk * 5 + g]), F[g], acc[yy], 0, 0, 0);
                }
            }
        }

        int zo = ztile + wz;
#pragma unroll
        for (int yy = 0; yy < YT; ++yy) {
            int yo = y0 + yy;
            long obase = ((((long)b * OCn + hi * 4) * Dm + zo) * Dm + yo) * Dm + x0 + n;
#pragma unroll
            for (int r = 0; r < 4; ++r)
                out[obase + (long)r * PL] = acc[yy][r] + ((const float*)&bv)[r];
        }

        if (t + 1 < NT) {
            asm volatile("s_waitcnt vmcnt(0)" ::: "memory");
            __syncthreads();
        }
    }
}

// ---------------- fallback conv (r6 structure, in-kernel staging) ------------
__global__ __launch_bounds__(256, 4)
void conv_fb_kernel(const float* __restrict__ x, const unsigned short* __restrict__ kwf,
                    const float* __restrict__ bias, float* __restrict__ out)
{
    __shared__ __align__(16) char smem[SPN*SSTR];

    const int NXT = Dm / XT, NYT = Dm / YT, NZT = Dm / ZT;    // 6, 12, 24
    int raw = blockIdx.x;
    int bid = (raw & 7) * ((BSn * NXT * NYT * NZT) / 8) + (raw >> 3);

    int txi = bid % NXT; bid /= NXT;
    int tyi = bid % NYT; bid /= NYT;
    int tzi = bid % NZT;
    int b   = bid / NZT;
    int x0 = txi * XT, y0 = tyi * YT, z0 = tzi * ZT;

    int tid  = threadIdx.x;
    int lane = tid & 63;
    int wz   = tid >> 6;

    const float* xb = x + (long)b * ICn * PL;

    for (int t = tid; t < 480; t += 256) {
        int xq  = t & 3;
        int ich = (t >> 2) & 1;
        int row = t >> 3;
        int ly = row % YL, lz = row / YL;
        int gz = z0 - 1 + lz, gy = y0 - 1 + ly;
        int gx = x0 + 4 * xq;
        bf16x8 v[4];
        if ((unsigned)gz < (unsigned)Dm && (unsigned)gy < (unsigned)Dm) {
            const float* g = xb + (long)(ich * 8) * PL + ((long)gz * Dm + gy) * Dm + gx;
#pragma unroll
            for (int q = 0; q < 8; ++q) {
                f32x4 p = *(const f32x4*)(g + (long)q * PL);
                v[0][q] = (__bf16)p.x; v[1][q] = (__bf16)p.y;
                v[2][q] = (__bf16)p.z; v[3][q] = (__bf16)p.w;
            }
        } else {
#pragma unroll
            for (int xi = 0; xi < 4; ++xi)
#pragma unroll
                for (int q = 0; q < 8; ++q) v[xi][q] = (__bf16)0.f;
        }
        int sp = (lz * YL + ly) * XL + (1 + 4 * xq);
#pragma unroll
        for (int xi = 0; xi < 4; ++xi)
            *(bf16x8*)(smem + (sp + xi) * SSTR + ich * 16) = v[xi];
    }
    for (int t = tid; t < 240; t += 256) {
        int s   = t & 1;
        int ich = (t >> 1) & 1;
        int row = t >> 2;
        int ly = row % YL, lz = row / YL;
        int gz = z0 - 1 + lz, gy = y0 - 1 + ly;
        int lx = s ? (XL - 1) : 0;
        int gx = x0 - 1 + lx;
        bf16x8 v;
        if ((unsigned)gz < (unsigned)Dm && (unsigned)gy < (unsigned)Dm &&
            (unsigned)gx < (unsigned)Dm) {
            const float* g = xb + (long)(ich * 8) * PL + ((long)gz * Dm + gy) * Dm + gx;
#pragma unroll
            for (int q = 0; q < 8; ++q) v[q] = (__bf16)g[(long)q * PL];
        } else {
#pragma unroll
            for (int q = 0; q < 8; ++q) v[q] = (__bf16)0.f;
        }
        int sp = (lz * YL + ly) * XL + lx;
        *(bf16x8*)(smem + sp * SSTR + ich * 16) = v;
    }

    const unsigned short* kwb = kwf + (long)b * FRAG_ELEMS;
    f32x4 afr[NG];
#pragma unroll
    for (int grp = 0; grp < NG; ++grp) {
        afr[grp] = *(const f32x4*)(kwb + (grp * 64 + lane) * 8);
        asm volatile("" : "+v"(afr[grp]));
    }

    __syncthreads();

    int n   = lane & 15;
    int hi  = lane >> 4;
    int cl  = hi >> 1;
    int ich = hi & 1;

    int addr_g[5];
#pragma unroll
    for (int g = 0; g < 5; ++g) {
        int c = 2 * g + cl;
        if (c > 8) c = 8;
        addr_g[g] = ((wz * YL) * XL + n) * SSTR + ich * 16 + coff(c);
    }

    f32x4 acc[YT];
#pragma unroll
    for (int yy = 0; yy < YT; ++yy) acc[yy] = (f32x4){0.f, 0.f, 0.f, 0.f};

#pragma unroll
    for (int p = 0; p < YL; ++p) {
        bf16x8 F[5];
#pragma unroll
        for (int g = 0; g < 5; ++g)
            F[g] = *(const bf16x8*)(smem + addr_g[g] + p * (XL * SSTR));
#pragma unroll
        for (int tyk = 0; tyk < 3; ++tyk) {
            int yy = p - tyk;
            if (yy >= 0 && yy < YT) {
#pragma unroll
                for (int g = 0; g < 5; ++g)
                    acc[yy] = __builtin_amdgcn_mfma_f32_16x16x32_bf16(
                        __builtin_bit_cast(bf16x8, afr[tyk * 5 + g]), F[g], acc[yy], 0, 0, 0);
            }
        }
    }

    float4 bv = *(const float4*)(bias + b * OCn + hi * 4);
    int zo = z0 + wz;
#pragma unroll
    for (int yy = 0; yy < YT; ++yy) {
        int yo = y0 + yy;
        long obase = ((((long)b * OCn + hi * 4) * Dm + zo) * Dm + yo) * Dm + x0 + n;
#pragma unroll
        for (int r = 0; r < 4; ++r)
            out[obase + (long)r * PL] = acc[yy][r] + ((const float*)&bv)[r];
    }
}

extern "C" void kernel_launch(void* const* d_in, const int* in_sizes, int n_in,
                              void* d_out, int out_size, void* d_ws, size_t ws_size,
                              hipStream_t stream)
{
    const float* x   = (const float*)d_in[0];
    const float* hyp = (const float*)d_in[1];
    const float* Wk  = (const float*)d_in[2];
    const float* bk  = (const float*)d_in[3];
    const float* Wb  = (const float*)d_in[4];
    const float* bb  = (const float*)d_in[5];
    float* out = (float*)d_out;

    const size_t need = XT_TOTAL + 61440 + 256;
    if (ws_size >= need) {
        char* xT = (char*)d_ws;
        unsigned short* kwf = (unsigned short*)(xT + XT_TOTAL);
        float* biasp = (float*)(xT + XT_TOTAL + 61440);

        hipLaunchKernelGGL(transpose_kernel, dim3(1544), dim3(256), 0, stream, x, xT);
        hipLaunchKernelGGL(hyper_frag_kernel, dim3((BSn * FRAG_ELEMS) / 256), dim3(256), 0, stream,
                           hyp, Wk, bk, kwf);
        hipLaunchKernelGGL(hyper_bias_kernel, dim3(1), dim3(64), 0, stream,
                           hyp, Wb, bb, biasp);
        hipLaunchKernelGGL(conv_dma_kernel, dim3(BSn * 6 * 12 * 6), dim3(256), 0, stream,
                           xT, kwf, biasp, out);
    } else {
        // fallback: workspace too small for xT — in-kernel staging (r6 path)
        unsigned short* kwf = (unsigned short*)d_ws;
        float* biasp = (float*)((char*)d_ws + (size_t)BSn * FRAG_ELEMS * 2);

        hipLaunchKernelGGL(hyper_frag_kernel, dim3((BSn * FRAG_ELEMS) / 256), dim3(256), 0, stream,
                           hyp, Wk, bk, kwf);
        hipLaunchKernelGGL(hyper_bias_kernel, dim3(1), dim3(64), 0, stream,
                           hyp, Wb, bb, biasp);
        hipLaunchKernelGGL(conv_fb_kernel, dim3(BSn * 6 * 12 * 24), dim3(256), 0, stream,
                           x, kwf, biasp, out);
    }
}

// Round 11
// 190.090 us; speedup vs baseline: 1.0794x; 1.0794x over previous
//
#include <hip/hip_runtime.h>

#define Dm 96
#define PL (Dm*Dm*Dm)               // 884736 elements per (b, ic) plane
#define ICn 16
#define OCn 16
#define HYPn 128
#define BSn 4
// K-packing: 15 groups of K=32. grp = ty*5 + g (ty = ky tap 0..2, g = 0..4).
// k_local = cl*16 + ic, cl in {0,1} -> (kz,kx) combo c = 2g+cl (c=9 is padding).
#define NG 15
#define FRAG_ELEMS (NG*64*8)        // 7680 bf16 per sample

// xT: bf16 [b][z:-1..96][y:-1..96][x:-1..96][16ic], 32B per point, zero halo.
#define XP 98
#define ROWB (XP*32)                // 3136
#define PLANEB (XP*ROWB)            // 307328
#define SAMPB ((size_t)XP*PLANEB)   // 30118144
#define XT_TOTAL ((size_t)4*SAMPB)  // 120472576

typedef float   f32x4  __attribute__((ext_vector_type(4)));
typedef __bf16  bf16x8 __attribute__((ext_vector_type(8)));

__device__ __forceinline__ unsigned short f2bf(float f) {
    unsigned u = __builtin_bit_cast(unsigned, f);
    u = (u + 0x7FFFu + ((u >> 16) & 1u)) >> 16;
    return (unsigned short)u;
}

// ---------------- fused pre-pass: transpose + hypernetwork ----------------
// With block index blk (after +boff offset):
// blk 0..1535:  transpose interior (b, z, y-quarter)
// blk 1536..1543: z-halo plane fills
// blk 1544..1663: hyper_frag (A-fragments in MFMA lane order)
// blk 1664: hyper bias
// Fallback mode launches with boff=1544 so only hyper blocks run.
__global__ __launch_bounds__(256)
void prep_kernel(const float* __restrict__ x, char* __restrict__ xT,
                 const float* __restrict__ hyp, const float* __restrict__ Wk,
                 const float* __restrict__ bk, unsigned short* __restrict__ kwf,
                 const float* __restrict__ Wb, const float* __restrict__ bb,
                 float* __restrict__ bias, int boff)
{
    int blk = blockIdx.x + boff;
    int tid = threadIdx.x;

    if (blk < 1536) {
        int yq = blk & 3;
        int z  = (blk >> 2) % Dm;
        int b  = (blk >> 2) / Dm;
        char* xTp = xT + (size_t)b*SAMPB + (size_t)(z+1)*PLANEB;
        const float* xb = x + (size_t)b*ICn*PL + (size_t)z*Dm*Dm;

        // interior: 1152 tasks = 2 ic-halves * 24 rows * 24 x-quads
        for (int t = tid; t < 1152; t += 256) {
            int ich = t & 1;
            int r   = t >> 1;
            int q = r % 24, yy = r / 24;
            int y = yq*24 + yy;
            const float* g = xb + (size_t)(ich*8)*PL + y*Dm + 4*q;
            f32x4 ld[8];
#pragma unroll
            for (int ic = 0; ic < 8; ++ic)
                ld[ic] = *(const f32x4*)(g + (size_t)ic*PL);
            char* w = xTp + (size_t)(y+1)*ROWB + (size_t)(1 + 4*q)*32 + ich*16;
#pragma unroll
            for (int xi = 0; xi < 4; ++xi) {
                bf16x8 v;
#pragma unroll
                for (int e = 0; e < 8; ++e) v[e] = (__bf16)ld[e][xi];
                *(bf16x8*)(w + xi*32) = v;
            }
        }
        bf16x8 z8;
#pragma unroll
        for (int i = 0; i < 8; ++i) z8[i] = (__bf16)0.f;
        for (int t = tid; t < 96; t += 256) {          // x-halo zeros
            int half = t & 1, side = (t >> 1) & 1, yy = t >> 2;
            int y = yq*24 + yy;
            *(bf16x8*)(xTp + (size_t)(y+1)*ROWB + (size_t)(side ? 97 : 0)*32 + half*16) = z8;
        }
        if (yq == 0 || yq == 3) {                       // y-halo rows
            char* w0 = xTp + (size_t)(yq == 0 ? 0 : 97)*ROWB;
            for (int t = tid; t < XP*2; t += 256)
                *(bf16x8*)(w0 + (size_t)t*16) = z8;
        }
        return;
    }
    if (blk < 1544) {                                   // z-halo planes
        int idx = blk - 1536;
        int b = idx >> 1, zb = idx & 1;
        char* p = xT + (size_t)b*SAMPB + (size_t)(zb ? 97 : 0)*PLANEB;
        f32x4 z4 = {0.f,0.f,0.f,0.f};
        for (int i = tid; i < PLANEB/16; i += 256)
            *(f32x4*)(p + (size_t)i*16) = z4;
        return;
    }
    if (blk < 1664) {                                   // hyper_frag
        int t = (blk - 1544) * 256 + tid;               // < 30720
        int j    = t & 7;
        int lane = (t >> 3) & 63;
        int rest = t >> 9;
        int grp  = rest % NG;
        int b    = rest / NG;
        int oc = lane & 15, hi = lane >> 4;
        int ty = grp / 5, g = grp % 5;
        int cl = hi >> 1;
        int ic = (hi & 1) * 8 + j;
        int c  = 2 * g + cl;
        float acc = 0.f;
        if (c < 9) {
            int tz = c / 3, tx = c % 3;
            int r = (oc * ICn + ic) * 27 + (tz * 9 + ty * 3 + tx);
            const float4* w = (const float4*)(Wk + (long)r * HYPn);
            const float4* h = (const float4*)(hyp + (long)b * HYPn);
            acc = bk[r];
#pragma unroll
            for (int q = 0; q < HYPn / 4; ++q) {
                float4 a = h[q], cc = w[q];
                acc += a.x * cc.x + a.y * cc.y + a.z * cc.z + a.w * cc.w;
            }
        }
        kwf[t] = f2bf(acc);
        return;
    }
    if (tid < 64) {                                     // bias
        int b = tid >> 4, oc = tid & 15;
        const float4* w = (const float4*)(Wb + (long)oc * HYPn);
        const float4* h = (const float4*)(hyp + (long)b * HYPn);
        float acc = bb[oc];
#pragma unroll
        for (int q = 0; q < HYPn / 4; ++q) {
            float4 a = h[q], c = w[q];
            acc += a.x * c.x + a.y * c.y + a.z * c.z + a.w * c.w;
        }
        bias[tid] = acc;
    }
}

// ---------------- MFMA conv: DMA-staged, double-buffered z-tile pipeline -----
#define ZT 4
#define YT 8
#define XT 16
#define ZL 6
#define YL 10
#define XL 18
#define SSTR 32
#define SPN (ZL*YL*XL)              // 1080
#define LPTS 1088                   // padded to DMA granularity
#define LDSB (LPTS*SSTR)            // 34816 per buffer
#define NDMA 34
#define NT 6
#define ZCH (ZT*NT)                 // 24

__device__ constexpr int coff(int c) {
    return ((c / 3) * YL * XL + (c % 3)) * SSTR;
}

__device__ __forceinline__ void dma_tile(const char* org, char* buf,
                                         const unsigned* goff, int wz, int lane)
{
#pragma unroll
    for (int m = 0; m < 9; ++m) {
        if (wz + 4*m < NDMA) {
            int i = wz + 4*m;
            __builtin_amdgcn_global_load_lds(
                (const __attribute__((address_space(1))) unsigned int*)(org + goff[m]),
                (__attribute__((address_space(3))) unsigned int*)(buf + i*1024 + lane*16),
                16, 0, 0);
        }
    }
}

__global__ __launch_bounds__(256, 2)
void conv_dma_kernel(const char* __restrict__ xT, const unsigned short* __restrict__ kwf,
                     const float* __restrict__ bias, float* __restrict__ out)
{
    __shared__ __align__(16) char smem[2*LDSB];

    const int NB = BSn * 6 * 12 * 4;                 // 1152
    int raw = blockIdx.x;
    int u = (raw & 7) * (NB/8) + (raw >> 3);         // XCD-contiguous

    int tx = u % 6;  u /= 6;
    int ty = u % 12; u /= 12;
    int zc = u % 4;
    int b  = u / 4;
    int x0 = tx*XT, y0 = ty*YT, zbase = zc*ZCH;

    int tid  = threadIdx.x;
    int lane = tid & 63;
    int wz   = tid >> 6;

    const unsigned short* kwb = kwf + (long)b * FRAG_ELEMS;
    f32x4 afr[NG];
#pragma unroll
    for (int grp = 0; grp < NG; ++grp) {
        afr[grp] = *(const f32x4*)(kwb + (grp * 64 + lane) * 8);
        asm volatile("" : "+v"(afr[grp]));
    }

    unsigned goff[9];
#pragma unroll
    for (int m = 0; m < 9; ++m) {
        int i = wz + 4*m;
        if (i >= NDMA) i = NDMA - 1;
        int flat = i*64 + lane;
        int p = flat >> 1;  if (p > 1079) p = 1079;
        int half = flat & 1;
        int lz = p / (YL*XL), r = p % (YL*XL), ly = r / XL, lx = r % XL;
        goff[m] = (unsigned)(lz*PLANEB + ly*ROWB + lx*32 + half*16);
    }

    int n   = lane & 15;
    int hi  = lane >> 4;
    int cl  = hi >> 1;
    int ich = hi & 1;

    int addr_g[5];
#pragma unroll
    for (int g = 0; g < 5; ++g) {
        int c = 2 * g + cl;
        if (c > 8) c = 8;
        addr_g[g] = ((wz * YL) * XL + n) * SSTR + ich * 16 + coff(c);
    }

    float4 bv = *(const float4*)(bias + b * OCn + hi * 4);

    const char* xsamp = xT + (size_t)b*SAMPB + (size_t)y0*ROWB + (size_t)x0*32;

    char* buf0 = smem;
    char* buf1 = smem + LDSB;

    dma_tile(xsamp + (size_t)zbase*PLANEB, buf0, goff, wz, lane);
    __syncthreads();

#pragma unroll
    for (int t = 0; t < NT; ++t) {
        char* cur = (t & 1) ? buf1 : buf0;
        char* nxt = (t & 1) ? buf0 : buf1;
        int ztile = zbase + t*ZT;

        if (t + 1 < NT) {
            dma_tile(xsamp + (size_t)(ztile + ZT)*PLANEB, nxt, goff, wz, lane);
            __builtin_amdgcn_sched_barrier(0);   // pin: 9 DMA issues precede all else
        }

        f32x4 acc[YT];
#pragma unroll
        for (int yy = 0; yy < YT; ++yy) acc[yy] = (f32x4){0.f,0.f,0.f,0.f};

#pragma unroll
        for (int p = 0; p < YL; ++p) {
            bf16x8 F[5];
#pragma unroll
            for (int g = 0; g < 5; ++g)
                F[g] = *(const bf16x8*)(cur + addr_g[g] + p * (XL * SSTR));
#pragma unroll
            for (int tyk = 0; tyk < 3; ++tyk) {
                int yy = p - tyk;
                if (yy >= 0 && yy < YT) {
#pragma unroll
                    for (int g = 0; g < 5; ++g)
                        acc[yy] = __builtin_amdgcn_mfma_f32_16x16x32_bf16(
                            __builtin_bit_cast(bf16x8, afr[tyk * 5 + g]), F[g], acc[yy], 0, 0, 0);
                }
            }
        }

        int zo = ztile + wz;
#pragma unroll
        for (int yy = 0; yy < YT; ++yy) {
            int yo = y0 + yy;
            long obase = ((((long)b * OCn + hi * 4) * Dm + zo) * Dm + yo) * Dm + x0 + n;
#pragma unroll
            for (int r = 0; r < 4; ++r)
                out[obase + (long)r * PL] = acc[yy][r] + ((const float*)&bv)[r];
        }

        if (t + 1 < NT) {
            // counted wait (T4): the 9 oldest VMEM ops (this tile's DMAs) must
            // land; the 32 output stores may stay in flight across the barrier.
            asm volatile("s_waitcnt vmcnt(32)" ::: "memory");
            __builtin_amdgcn_s_barrier();
            __builtin_amdgcn_sched_barrier(0);
        }
    }
}

// ---------------- fallback conv (r6 structure, in-kernel staging) ------------
__global__ __launch_bounds__(256, 4)
void conv_fb_kernel(const float* __restrict__ x, const unsigned short* __restrict__ kwf,
                    const float* __restrict__ bias, float* __restrict__ out)
{
    __shared__ __align__(16) char smem[SPN*SSTR];

    const int NXT = Dm / XT, NYT = Dm / YT, NZT = Dm / ZT;    // 6, 12, 24
    int raw = blockIdx.x;
    int bid = (raw & 7) * ((BSn * NXT * NYT * NZT) / 8) + (raw >> 3);

    int txi = bid % NXT; bid /= NXT;
    int tyi = bid % NYT; bid /= NYT;
    int tzi = bid % NZT;
    int b   = bid / NZT;
    int x0 = txi * XT, y0 = tyi * YT, z0 = tzi * ZT;

    int tid  = threadIdx.x;
    int lane = tid & 63;
    int wz   = tid >> 6;

    const float* xb = x + (long)b * ICn * PL;

    for (int t = tid; t < 480; t += 256) {
        int xq  = t & 3;
        int ich = (t >> 2) & 1;
        int row = t >> 3;
        int ly = row % YL, lz = row / YL;
        int gz = z0 - 1 + lz, gy = y0 - 1 + ly;
        int gx = x0 + 4 * xq;
        bf16x8 v[4];
        if ((unsigned)gz < (unsigned)Dm && (unsigned)gy < (unsigned)Dm) {
            const float* g = xb + (long)(ich * 8) * PL + ((long)gz * Dm + gy) * Dm + gx;
#pragma unroll
            for (int q = 0; q < 8; ++q) {
                f32x4 p = *(const f32x4*)(g + (long)q * PL);
                v[0][q] = (__bf16)p.x; v[1][q] = (__bf16)p.y;
                v[2][q] = (__bf16)p.z; v[3][q] = (__bf16)p.w;
            }
        } else {
#pragma unroll
            for (int xi = 0; xi < 4; ++xi)
#pragma unroll
                for (int q = 0; q < 8; ++q) v[xi][q] = (__bf16)0.f;
        }
        int sp = (lz * YL + ly) * XL + (1 + 4 * xq);
#pragma unroll
        for (int xi = 0; xi < 4; ++xi)
            *(bf16x8*)(smem + (sp + xi) * SSTR + ich * 16) = v[xi];
    }
    for (int t = tid; t < 240; t += 256) {
        int s   = t & 1;
        int ich = (t >> 1) & 1;
        int row = t >> 2;
        int ly = row % YL, lz = row / YL;
        int gz = z0 - 1 + lz, gy = y0 - 1 + ly;
        int lx = s ? (XL - 1) : 0;
        int gx = x0 - 1 + lx;
        bf16x8 v;
        if ((unsigned)gz < (unsigned)Dm && (unsigned)gy < (unsigned)Dm &&
            (unsigned)gx < (unsigned)Dm) {
            const float* g = xb + (long)(ich * 8) * PL + ((long)gz * Dm + gy) * Dm + gx;
#pragma unroll
            for (int q = 0; q < 8; ++q) v[q] = (__bf16)g[(long)q * PL];
        } else {
#pragma unroll
            for (int q = 0; q < 8; ++q) v[q] = (__bf16)0.f;
        }
        int sp = (lz * YL + ly) * XL + lx;
        *(bf16x8*)(smem + sp * SSTR + ich * 16) = v;
    }

    const unsigned short* kwb = kwf + (long)b * FRAG_ELEMS;
    f32x4 afr[NG];
#pragma unroll
    for (int grp = 0; grp < NG; ++grp) {
        afr[grp] = *(const f32x4*)(kwb + (grp * 64 + lane) * 8);
        asm volatile("" : "+v"(afr[grp]));
    }

    __syncthreads();

    int n   = lane & 15;
    int hi  = lane >> 4;
    int cl  = hi >> 1;
    int ich = hi & 1;

    int addr_g[5];
#pragma unroll
    for (int g = 0; g < 5; ++g) {
        int c = 2 * g + cl;
        if (c > 8) c = 8;
        addr_g[g] = ((wz * YL) * XL + n) * SSTR + ich * 16 + coff(c);
    }

    f32x4 acc[YT];
#pragma unroll
    for (int yy = 0; yy < YT; ++yy) acc[yy] = (f32x4){0.f, 0.f, 0.f, 0.f};

#pragma unroll
    for (int p = 0; p < YL; ++p) {
        bf16x8 F[5];
#pragma unroll
        for (int g = 0; g < 5; ++g)
            F[g] = *(const bf16x8*)(smem + addr_g[g] + p * (XL * SSTR));
#pragma unroll
        for (int tyk = 0; tyk < 3; ++tyk) {
            int yy = p - tyk;
            if (yy >= 0 && yy < YT) {
#pragma unroll
                for (int g = 0; g < 5; ++g)
                    acc[yy] = __builtin_amdgcn_mfma_f32_16x16x32_bf16(
                        __builtin_bit_cast(bf16x8, afr[tyk * 5 + g]), F[g], acc[yy], 0, 0, 0);
            }
        }
    }

    float4 bv = *(const float4*)(bias + b * OCn + hi * 4);
    int zo = z0 + wz;
#pragma unroll
    for (int yy = 0; yy < YT; ++yy) {
        int yo = y0 + yy;
        long obase = ((((long)b * OCn + hi * 4) * Dm + zo) * Dm + yo) * Dm + x0 + n;
#pragma unroll
        for (int r = 0; r < 4; ++r)
            out[obase + (long)r * PL] = acc[yy][r] + ((const float*)&bv)[r];
    }
}

extern "C" void kernel_launch(void* const* d_in, const int* in_sizes, int n_in,
                              void* d_out, int out_size, void* d_ws, size_t ws_size,
                              hipStream_t stream)
{
    const float* x   = (const float*)d_in[0];
    const float* hyp = (const float*)d_in[1];
    const float* Wk  = (const float*)d_in[2];
    const float* bk  = (const float*)d_in[3];
    const float* Wb  = (const float*)d_in[4];
    const float* bb  = (const float*)d_in[5];
    float* out = (float*)d_out;

    const size_t need = XT_TOTAL + 61440 + 256;
    if (ws_size >= need) {
        char* xT = (char*)d_ws;
        unsigned short* kwf = (unsigned short*)(xT + XT_TOTAL);
        float* biasp = (float*)(xT + XT_TOTAL + 61440);

        hipLaunchKernelGGL(prep_kernel, dim3(1665), dim3(256), 0, stream,
                           x, xT, hyp, Wk, bk, kwf, Wb, bb, biasp, 0);
        hipLaunchKernelGGL(conv_dma_kernel, dim3(BSn * 6 * 12 * 4), dim3(256), 0, stream,
                           xT, kwf, biasp, out);
    } else {
        // fallback: workspace too small for xT — hyper blocks only + r6 conv
        unsigned short* kwf = (unsigned short*)d_ws;
        float* biasp = (float*)((char*)d_ws + (size_t)BSn * FRAG_ELEMS * 2);

        hipLaunchKernelGGL(prep_kernel, dim3(121), dim3(256), 0, stream,
                           x, (char*)d_ws, hyp, Wk, bk, kwf, Wb, bb, biasp, 1544);
        hipLaunchKernelGGL(conv_fb_kernel, dim3(BSn * 6 * 12 * 24), dim3(256), 0, stream,
                           x, kwf, biasp, out);
    }
}